// Round 3
// baseline (461.603 us; speedup 1.0000x reference)
//
#include <hip/hip_runtime.h>
#include <math.h>

// Problem constants (S, B, D from reference).
#define S_LEN   2048
#define BATCH   32
#define DIM     1024
#define P_CHUNKS 32                 // seq-split for flash-style partials
#define CHUNK   (S_LEN / P_CHUNKS)  // 64 rows per block
#define RPW     (CHUNK / 4)         // 16 rows per wave

// ---------------------------------------------------------------------------
// Skinny GEMM: out[b][d] = act( sum_k A[b][k] * W[d][k] ), b in [0,32).
// One wave per output column d (4 waves/block -> grid = Dout/4 = 256 blocks,
// exactly 1 block/CU). A is staged in LDS in 1024-wide K phases (128 KiB),
// so K=1024 needs 1 stage (2 barriers) and K=2048 needs 2 (3 barriers);
// the compute loop is barrier-free pipelined ds_read_b128.
// act: 0 = identity, 1 = tanh.
// ---------------------------------------------------------------------------
__global__ __launch_bounds__(256) void gemm_skinny(
    const float* __restrict__ A, const float* __restrict__ W,
    float* __restrict__ out, int K, int Dout, int act)
{
    __shared__ __align__(16) float At[32 * 1024];  // 128 KiB

    const int t    = threadIdx.x;
    const int lane = t & 63;
    const int wid  = t >> 6;
    const int d    = blockIdx.x * 4 + wid;

    float acc[32];
#pragma unroll
    for (int b = 0; b < 32; ++b) acc[b] = 0.0f;

    for (int k0 = 0; k0 < K; k0 += 1024) {
        if (k0) __syncthreads();  // protect LDS before re-stage
        // Stage 32 rows x 1024 floats: thread t copies float4 t of row i.
#pragma unroll 8
        for (int i = 0; i < 32; ++i) {
            ((float4*)At)[i * 256 + t] =
                ((const float4*)(A + (size_t)i * K + k0))[t];
        }
        __syncthreads();

        // Barrier-free compute over this K phase: 4 chunks of 256 floats.
#pragma unroll
        for (int c = 0; c < 4; ++c) {
            float4 w4 =
                ((const float4*)(W + (size_t)d * K + k0 + c * 256))[lane];
#pragma unroll
            for (int b = 0; b < 32; ++b) {
                float4 a4 = ((const float4*)At)[b * 256 + c * 64 + lane];
                acc[b] = fmaf(w4.x, a4.x, acc[b]);
                acc[b] = fmaf(w4.y, a4.y, acc[b]);
                acc[b] = fmaf(w4.z, a4.z, acc[b]);
                acc[b] = fmaf(w4.w, a4.w, acc[b]);
            }
        }
    }

    // Reduce each acc[b] across the 64 lanes; lane b keeps batch b's result.
    float mine = 0.0f;
#pragma unroll
    for (int b = 0; b < 32; ++b) {
        float v = acc[b];
#pragma unroll
        for (int off = 32; off > 0; off >>= 1) v += __shfl_xor(v, off, 64);
        if (lane == b) mine = v;
    }
    if (lane < 32) {
        float o = act ? tanhf(mine) : mine;
        out[(size_t)lane * Dout + d] = o;
    }
}

// ---------------------------------------------------------------------------
// Flash-style fused logits + online softmax + weighted-sum partials.
// Block = 256 threads = 4 waves handles CHUNK=64 seq rows of one batch b.
// Each WAVE independently processes 16 rows, TWO per iteration: 8 float4
// loads in flight, two independent 6-step shuffle butterflies, one shared
// online-softmax rescale per pair (halves the serial exp/rescale chain).
// No barriers in the main loop; one LDS merge of the 4 wave partials at
// the end. __launch_bounds__(256,4) pins VGPR<=128 so 4 blocks/CU fit.
// ---------------------------------------------------------------------------
__global__ __launch_bounds__(256, 4) void attn_partial(
    const float* __restrict__ input, const float* __restrict__ semi,
    float* __restrict__ pacc, float* __restrict__ pm, float* __restrict__ pl)
{
    const int p    = blockIdx.x;   // seq chunk
    const int b    = blockIdx.y;   // batch
    const int t    = threadIdx.x;
    const int lane = t & 63;
    const int w    = t >> 6;
    const int s0   = p * CHUNK + w * RPW;   // this wave's first seq row

    __shared__ float  wm[4], wl[4];
    __shared__ __align__(16) float4 bacc[4 * 256];  // 16 KiB

    // semi fragment, same layout as accumulator: col4 = lane + 64*j
    const float4* sm = (const float4*)(semi + (size_t)b * DIM);
    float4 s4[4];
#pragma unroll
    for (int j = 0; j < 4; ++j) s4[j] = sm[lane + 64 * j];

    const float4* base =
        (const float4*)(input + ((size_t)s0 * BATCH + b) * DIM);
    const int rstride = BATCH * DIM / 4;  // 8192 float4 between seq rows

    float m = -INFINITY, l = 0.0f;
    float4 acc[4];
#pragma unroll
    for (int j = 0; j < 4; ++j) acc[j] = make_float4(0.f, 0.f, 0.f, 0.f);

    float4 x0[4], x1[4], n0[4], n1[4];
#pragma unroll
    for (int j = 0; j < 4; ++j) {            // prefetch rows 0,1
        n0[j] = base[lane + 64 * j];
        n1[j] = base[rstride + lane + 64 * j];
    }

#pragma unroll
    for (int i = 0; i < RPW; i += 2) {
#pragma unroll
        for (int j = 0; j < 4; ++j) { x0[j] = n0[j]; x1[j] = n1[j]; }
        if (i + 2 < RPW) {
#pragma unroll
            for (int j = 0; j < 4; ++j) {
                n0[j] = base[(i + 2) * rstride + lane + 64 * j];
                n1[j] = base[(i + 3) * rstride + lane + 64 * j];
            }
        }

        float p0 = 0.0f, p1 = 0.0f;
#pragma unroll
        for (int j = 0; j < 4; ++j) {
            p0 = fmaf(x0[j].x, s4[j].x, p0);
            p1 = fmaf(x1[j].x, s4[j].x, p1);
            p0 = fmaf(x0[j].y, s4[j].y, p0);
            p1 = fmaf(x1[j].y, s4[j].y, p1);
            p0 = fmaf(x0[j].z, s4[j].z, p0);
            p1 = fmaf(x1[j].z, s4[j].z, p1);
            p0 = fmaf(x0[j].w, s4[j].w, p0);
            p1 = fmaf(x1[j].w, s4[j].w, p1);
        }
#pragma unroll
        for (int off = 32; off > 0; off >>= 1) {
            p0 += __shfl_xor(p0, off, 64);   // two independent butterflies,
            p1 += __shfl_xor(p1, off, 64);   // interleaved for ILP
        }

        float mn = fmaxf(m, fmaxf(p0, p1));
        float sc = __expf(m - mn);   // 0 on first pair (m = -inf)
        float f0 = __expf(p0 - mn);
        float f1 = __expf(p1 - mn);
#pragma unroll
        for (int j = 0; j < 4; ++j) {
            acc[j].x = fmaf(f1, x1[j].x, fmaf(f0, x0[j].x, acc[j].x * sc));
            acc[j].y = fmaf(f1, x1[j].y, fmaf(f0, x0[j].y, acc[j].y * sc));
            acc[j].z = fmaf(f1, x1[j].z, fmaf(f0, x0[j].z, acc[j].z * sc));
            acc[j].w = fmaf(f1, x1[j].w, fmaf(f0, x0[j].w, acc[j].w * sc));
        }
        l = fmaf(l, sc, f0 + f1);
        m = mn;
    }

    // Cross-wave merge: rescale each wave's partial to the block max.
    if (lane == 0) { wm[w] = m; wl[w] = l; }
    __syncthreads();
    float M = fmaxf(fmaxf(wm[0], wm[1]), fmaxf(wm[2], wm[3]));
    float fw = __expf(m - M);  // wave-uniform
#pragma unroll
    for (int j = 0; j < 4; ++j) {
        float4 a = acc[j];
        a.x *= fw; a.y *= fw; a.z *= fw; a.w *= fw;
        bacc[w * 256 + lane + 64 * j] = a;
    }
    __syncthreads();

    float4 o0 = bacc[t],        o1 = bacc[256 + t];
    float4 o2 = bacc[512 + t],  o3 = bacc[768 + t];
    float4 o = make_float4(o0.x + o1.x + o2.x + o3.x,
                           o0.y + o1.y + o2.y + o3.y,
                           o0.z + o1.z + o2.z + o3.z,
                           o0.w + o1.w + o2.w + o3.w);
    ((float4*)(pacc + ((size_t)b * P_CHUNKS + p) * DIM))[t] = o;

    if (t == 0) {
        float L = 0.0f;
#pragma unroll
        for (int ww = 0; ww < 4; ++ww)
            L = fmaf(wl[ww], __expf(wm[ww] - M), L);
        pm[b * P_CHUNKS + p] = M;
        pl[b * P_CHUNKS + p] = L;
    }
}

// ---------------------------------------------------------------------------
// Combine partials for batch b; write s_tilde into cat[:, :1024] and copy h
// into cat[:, 1024:]. Grid (32 batches x 4 d-quarters), 256 threads.
// ---------------------------------------------------------------------------
__global__ __launch_bounds__(256) void combine(
    const float* __restrict__ pacc, const float* __restrict__ pm,
    const float* __restrict__ pl, const float* __restrict__ h,
    float* __restrict__ cat)
{
    const int b = blockIdx.x;
    const int q = blockIdx.y;
    const int t = threadIdx.x;

    __shared__ float fsc[32];
    __shared__ float smv[32], slv[32];
    __shared__ float Linv;

    if (t < 32) {
        smv[t] = pm[b * P_CHUNKS + t];
        slv[t] = pl[b * P_CHUNKS + t];
    }
    __syncthreads();
    if (t == 0) {
        float M = -INFINITY;
        for (int pp = 0; pp < 32; ++pp) M = fmaxf(M, smv[pp]);
        float L = 0.0f;
        for (int pp = 0; pp < 32; ++pp) {
            float f = __expf(smv[pp] - M);
            fsc[pp] = f;
            L = fmaf(slv[pp], f, L);
        }
        Linv = 1.0f / L;
    }
    __syncthreads();

    const int d = q * 256 + t;
    float sum = 0.0f;
#pragma unroll
    for (int pp = 0; pp < 32; ++pp)
        sum = fmaf(fsc[pp], pacc[((size_t)b * P_CHUNKS + pp) * DIM + d], sum);

    cat[(size_t)b * (2 * DIM) + d]       = sum * Linv;
    cat[(size_t)b * (2 * DIM) + DIM + d] = h[(size_t)b * DIM + d];
}

// ---------------------------------------------------------------------------
extern "C" void kernel_launch(void* const* d_in, const int* in_sizes, int n_in,
                              void* d_out, int out_size, void* d_ws, size_t ws_size,
                              hipStream_t stream)
{
    const float* input = (const float*)d_in[0];  // [S, B, D]
    const float* h     = (const float*)d_in[1];  // [B, D]
    const float* Wi    = (const float*)d_in[2];  // [D, D]
    const float* Wo    = (const float*)d_in[3];  // [D, 2D]
    float* out = (float*)d_out;                  // [B, D]

    // Workspace carve (floats): semi | pacc | pm | pl | cat  (~4.4 MiB)
    float* ws   = (float*)d_ws;
    float* semi = ws;                                   // 32*1024
    float* pacc = semi + 32 * 1024;                     // 32*32*1024
    float* pm   = pacc + 32 * 32 * 1024;                // 1024
    float* pl   = pm + 1024;                            // 1024
    float* cat  = pl + 1024;                            // 32*2048

    // 1) semi = h @ Wi.T   (K=1024, Dout=1024)
    hipLaunchKernelGGL(gemm_skinny, dim3(256), dim3(256), 0, stream,
                       h, Wi, semi, 1024, 1024, 0);
    // 2) fused logits + online softmax + weighted-sum partials (reads input once)
    hipLaunchKernelGGL(attn_partial, dim3(P_CHUNKS, BATCH), dim3(256), 0, stream,
                       input, semi, pacc, pm, pl);
    // 3) combine partials -> cat = [s_tilde, h]
    hipLaunchKernelGGL(combine, dim3(BATCH, 4), dim3(256), 0, stream,
                       pacc, pm, pl, h, cat);
    // 4) out = tanh(cat @ Wo.T)   (K=2048, Dout=1024)
    hipLaunchKernelGGL(gemm_skinny, dim3(256), dim3(256), 0, stream,
                       cat, Wo, out, 2048, 1024, 1);
}

// Round 4
// 422.956 us; speedup vs baseline: 1.0914x; 1.0914x over previous
//
#include <hip/hip_runtime.h>
#include <math.h>

// Problem constants (S, B, D from reference).
#define S_LEN   2048
#define BATCH   32
#define DIM     1024
#define P_CHUNKS 64                 // seq-split for flash-style partials
#define CHUNK   (S_LEN / P_CHUNKS)  // 32 rows per wave

// ---------------------------------------------------------------------------
// Skinny GEMM: out[b][d] = act( sum_k A[b][k] * W[d][k] ), b in [0,32).
// One wave per output column d (4 waves/block -> grid = Dout/4 blocks).
// A (32 x K) is staged in LDS in 256-wide K tiles; W is streamed coalesced.
// act: 0 = identity, 1 = tanh.   (32 KiB LDS tile: 2+ blocks/CU fit.)
// ---------------------------------------------------------------------------
__global__ __launch_bounds__(256) void gemm_skinny(
    const float* __restrict__ A, const float* __restrict__ W,
    float* __restrict__ out, int K, int Dout, int act)
{
    __shared__ __align__(16) float At[32 * 256];  // 32 KiB

    const int t    = threadIdx.x;
    const int lane = t & 63;
    const int wid  = t >> 6;
    const int d    = blockIdx.x * 4 + wid;

    float acc[32];
#pragma unroll
    for (int b = 0; b < 32; ++b) acc[b] = 0.0f;

    for (int k0 = 0; k0 < K; k0 += 256) {
        // Stage A tile: 8192 floats = 2048 float4, 8 per thread, coalesced.
#pragma unroll
        for (int i = 0; i < 8; ++i) {
            int f4id = t + i * 256;
            int bb   = f4id >> 6;       // row (batch)
            int c4   = f4id & 63;       // float4 column within tile
            ((float4*)At)[bb * 64 + c4] =
                ((const float4*)(A + (size_t)bb * K + k0))[c4];
        }
        __syncthreads();

        // Wave reads its W row slice (coalesced float4).
        float4 w4 = ((const float4*)(W + (size_t)d * K + k0))[lane];

#pragma unroll
        for (int b = 0; b < 32; ++b) {
            float4 a4 = ((const float4*)At)[b * 64 + lane];
            acc[b] = fmaf(w4.x, a4.x, acc[b]);
            acc[b] = fmaf(w4.y, a4.y, acc[b]);
            acc[b] = fmaf(w4.z, a4.z, acc[b]);
            acc[b] = fmaf(w4.w, a4.w, acc[b]);
        }
        __syncthreads();
    }

    // Reduce each acc[b] across the 64 lanes; lane b keeps batch b's result.
    float mine = 0.0f;
#pragma unroll
    for (int b = 0; b < 32; ++b) {
        float v = acc[b];
#pragma unroll
        for (int off = 32; off > 0; off >>= 1) v += __shfl_xor(v, off, 64);
        if (lane == b) mine = v;
    }
    if (lane < 32) {
        float o = act ? tanhf(mine) : mine;
        out[(size_t)lane * Dout + d] = o;
    }
}

// ---------------------------------------------------------------------------
// Flash-style fused logits + online softmax + weighted-sum partials.
// Block = 512 threads = 8 waves. Block (p,g) covers seq rows
// [32p, 32p+32) x batches [8g, 8g+8); wave w owns batch 8g+w. The 8
// co-resident waves read ADJACENT batch slices, so the block's per-row
// footprint is 32 KiB CONTIGUOUS (vs the old scattered 4 KiB chunks) —
// DRAM-friendly. Each wave is fully independent: full-row dot (lane holds
// 16 features), 6-step shuffle butterfly -> logit in all lanes, online
// softmax with wave-uniform skip of the rescale when max doesn't grow.
// No LDS, no barriers. Writes partial (m, l, acc[1024]) per (b, p).
// ---------------------------------------------------------------------------
__global__ __launch_bounds__(512) void attn_partial(
    const float* __restrict__ input, const float* __restrict__ semi,
    float* __restrict__ pacc, float* __restrict__ pm, float* __restrict__ pl)
{
    const int p    = blockIdx.x;        // seq chunk [0,64)
    const int g    = blockIdx.y;        // batch group [0,4)
    const int t    = threadIdx.x;
    const int lane = t & 63;
    const int w    = t >> 6;            // wave [0,8)
    const int b    = g * 8 + w;         // this wave's batch
    const int s0   = p * CHUNK;

    // semi fragment, same layout as accumulator: col4 = lane + 64*j
    const float4* sm = (const float4*)(semi + (size_t)b * DIM);
    float4 s4[4];
#pragma unroll
    for (int j = 0; j < 4; ++j) s4[j] = sm[lane + 64 * j];

    const float4* base =
        (const float4*)(input + ((size_t)s0 * BATCH + b) * DIM);
    const int rstride = BATCH * DIM / 4;  // 8192 float4 between seq rows

    float m = -INFINITY, l = 0.0f;
    float4 acc[4];
#pragma unroll
    for (int j = 0; j < 4; ++j) acc[j] = make_float4(0.f, 0.f, 0.f, 0.f);

    float4 xA[4], xB[4];
#pragma unroll
    for (int j = 0; j < 4; ++j) xA[j] = base[lane + 64 * j];            // row 0
#pragma unroll
    for (int j = 0; j < 4; ++j) xB[j] = base[rstride + lane + 64 * j];  // row 1

#define ATTN_STEP(X)                                                      \
    do {                                                                  \
        float pd = 0.0f;                                                  \
        _Pragma("unroll")                                                 \
        for (int j = 0; j < 4; ++j) {                                     \
            pd = fmaf((X)[j].x, s4[j].x, pd);                             \
            pd = fmaf((X)[j].y, s4[j].y, pd);                             \
            pd = fmaf((X)[j].z, s4[j].z, pd);                             \
            pd = fmaf((X)[j].w, s4[j].w, pd);                             \
        }                                                                 \
        _Pragma("unroll")                                                 \
        for (int off = 32; off > 0; off >>= 1)                            \
            pd += __shfl_xor(pd, off, 64);                                \
        if (pd <= m) {              /* wave-uniform: no rescale needed */ \
            float f = __expf(pd - m);                                     \
            _Pragma("unroll")                                             \
            for (int j = 0; j < 4; ++j) {                                 \
                acc[j].x = fmaf(f, (X)[j].x, acc[j].x);                   \
                acc[j].y = fmaf(f, (X)[j].y, acc[j].y);                   \
                acc[j].z = fmaf(f, (X)[j].z, acc[j].z);                   \
                acc[j].w = fmaf(f, (X)[j].w, acc[j].w);                   \
            }                                                             \
            l += f;                                                       \
        } else {                    /* new max: f == 1, rescale by sc */  \
            float sc = __expf(m - pd);  /* 0 on first row (m=-inf) */     \
            _Pragma("unroll")                                             \
            for (int j = 0; j < 4; ++j) {                                 \
                acc[j].x = fmaf(acc[j].x, sc, (X)[j].x);                  \
                acc[j].y = fmaf(acc[j].y, sc, (X)[j].y);                  \
                acc[j].z = fmaf(acc[j].z, sc, (X)[j].z);                  \
                acc[j].w = fmaf(acc[j].w, sc, (X)[j].w);                  \
            }                                                             \
            l = fmaf(l, sc, 1.0f);                                        \
            m = pd;                                                       \
        }                                                                 \
    } while (0)

    for (int i = 0; i < CHUNK; i += 2) {
        ATTN_STEP(xA);                         // row i (xB for i+1 in flight)
        if (i + 2 < CHUNK) {
#pragma unroll
            for (int j = 0; j < 4; ++j)
                xA[j] = base[(i + 2) * rstride + lane + 64 * j];
        }
        ATTN_STEP(xB);                         // row i+1 (xA refill in flight)
        if (i + 3 < CHUNK) {
#pragma unroll
            for (int j = 0; j < 4; ++j)
                xB[j] = base[(i + 3) * rstride + lane + 64 * j];
        }
    }
#undef ATTN_STEP

    // Each wave writes its own partial — no cross-wave merge needed.
    float4* op = (float4*)(pacc + ((size_t)b * P_CHUNKS + p) * DIM);
#pragma unroll
    for (int j = 0; j < 4; ++j) op[lane + 64 * j] = acc[j];
    if (lane == 0) {
        pm[b * P_CHUNKS + p] = m;
        pl[b * P_CHUNKS + p] = l;
    }
}

// ---------------------------------------------------------------------------
// Combine 64 partials per batch b; write s_tilde into cat[:, :1024] and copy
// h into cat[:, 1024:]. Grid (32 batches x 4 d-quarters), 256 threads.
// ---------------------------------------------------------------------------
__global__ __launch_bounds__(256) void combine(
    const float* __restrict__ pacc, const float* __restrict__ pm,
    const float* __restrict__ pl, const float* __restrict__ h,
    float* __restrict__ cat)
{
    const int b = blockIdx.x;
    const int q = blockIdx.y;
    const int t = threadIdx.x;

    __shared__ float fsc[P_CHUNKS];
    __shared__ float smv[P_CHUNKS], slv[P_CHUNKS];
    __shared__ float Linv;

    if (t < P_CHUNKS) {
        smv[t] = pm[b * P_CHUNKS + t];
        slv[t] = pl[b * P_CHUNKS + t];
    }
    __syncthreads();
    if (t == 0) {
        float M = -INFINITY;
        for (int pp = 0; pp < P_CHUNKS; ++pp) M = fmaxf(M, smv[pp]);
        float L = 0.0f;
        for (int pp = 0; pp < P_CHUNKS; ++pp) {
            float f = __expf(smv[pp] - M);
            fsc[pp] = f;
            L = fmaf(slv[pp], f, L);
        }
        Linv = 1.0f / L;
    }
    __syncthreads();

    const int d = q * 256 + t;
    float sum = 0.0f;
#pragma unroll
    for (int pp = 0; pp < P_CHUNKS; ++pp)
        sum = fmaf(fsc[pp], pacc[((size_t)b * P_CHUNKS + pp) * DIM + d], sum);

    cat[(size_t)b * (2 * DIM) + d]       = sum * Linv;
    cat[(size_t)b * (2 * DIM) + DIM + d] = h[(size_t)b * DIM + d];
}

// ---------------------------------------------------------------------------
extern "C" void kernel_launch(void* const* d_in, const int* in_sizes, int n_in,
                              void* d_out, int out_size, void* d_ws, size_t ws_size,
                              hipStream_t stream)
{
    const float* input = (const float*)d_in[0];  // [S, B, D]
    const float* h     = (const float*)d_in[1];  // [B, D]
    const float* Wi    = (const float*)d_in[2];  // [D, D]
    const float* Wo    = (const float*)d_in[3];  // [D, 2D]
    float* out = (float*)d_out;                  // [B, D]

    // Workspace carve (floats): semi | pacc | pm | pl | cat  (~8.6 MiB)
    float* ws   = (float*)d_ws;
    float* semi = ws;                                    // 32*1024
    float* pacc = semi + 32 * 1024;                      // 32*64*1024
    float* pm   = pacc + 32 * P_CHUNKS * 1024;           // 2048
    float* pl   = pm + 32 * P_CHUNKS;                    // 2048
    float* cat  = pl + 32 * P_CHUNKS;                    // 32*2048

    // 1) semi = h @ Wi.T   (K=1024, Dout=1024)
    hipLaunchKernelGGL(gemm_skinny, dim3(256), dim3(256), 0, stream,
                       h, Wi, semi, 1024, 1024, 0);
    // 2) fused logits + online softmax + weighted-sum partials (reads input once)
    hipLaunchKernelGGL(attn_partial, dim3(P_CHUNKS, 4), dim3(512), 0, stream,
                       input, semi, pacc, pm, pl);
    // 3) combine partials -> cat = [s_tilde, h]
    hipLaunchKernelGGL(combine, dim3(BATCH, 4), dim3(256), 0, stream,
                       pacc, pm, pl, h, cat);
    // 4) out = tanh(cat @ Wo.T)   (K=2048, Dout=1024)
    hipLaunchKernelGGL(gemm_skinny, dim3(256), dim3(256), 0, stream,
                       cat, Wo, out, 2048, 1024, 1);
}